// Round 7
// baseline (366.870 us; speedup 1.0000x reference)
//
#include <hip/hip_runtime.h>
#include <math.h>
#include <float.h>

#define BN 32
#define CH 3
#define HH 512
#define WW 512
#define NP 4
#define EPS 128
#define HALF 64
#define MARGIN 32

#define PATCH_ELEMS (BN * NP * CH * EPS * EPS)   // 6291456
#define NT 4096          // 64x64 grid of 8x8 tiles per map
#define TPR 64
#define NBLK 256         // 8 blocks per map, all on the same XCD (32 % 8 == 0)
#define NTHR 512
#define F4_PER_MAP (NP * CH * EPS * EPS / 4)     // 49152
#define F4_PER_SLICE (F4_PER_MAP / 8)            // 6144 = 12 * 512

// pack (value, index): value >= 0 so float bits are order-preserving;
// ~idx in low bits => equal values tie-break to SMALLEST index (row-major first).
__device__ __forceinline__ unsigned long long pack_vi(float v, int idx) {
    return ((unsigned long long)__float_as_uint(v) << 32) |
           (unsigned long long)(0xffffffffu - (unsigned)idx);
}

__global__ __launch_bounds__(NTHR)
void fused_kernel(const float* __restrict__ images,
                  const float* __restrict__ umaps,
                  float* __restrict__ out)          // patches then coords
{
    const int tid   = threadIdx.x;
    const int lane  = tid & 63;
    const int wave  = tid >> 6;
    const int b     = blockIdx.x & (BN - 1);
    const int slice = blockIdx.x >> 5;
    const float* __restrict__ um = umaps + (size_t)b * HH * WW;
    float* coords_out = out + PATCH_ELEMS;

    __shared__ unsigned long long rw[8];
    __shared__ int boxes[NP][4];     // clipped, margin-expanded ex1,ex2,ey1,ey2
    __shared__ int sx1[NP], sy1[NP];

    // ======== Phase 1: scan own map, 8 tiles/thread, packed in registers ====
    unsigned long long pv[8];
    const int tx = tid & (TPR - 1);
    const int X1 = tx << 3;
    #pragma unroll
    for (int i = 0; i < 8; ++i) {
        const int ty = (tid >> 6) + (i << 3);     // tile t = (i<<9)+tid
        const int y0 = ty << 3;
        float bv = -INFINITY; int bi = 0x7fffffff;
        #pragma unroll
        for (int r = 0; r < 8; ++r) {
            const int rowbase = (y0 + r) * WW + X1;
            const float4 a = *(const float4*)(um + rowbase);
            const float4 c = *(const float4*)(um + rowbase + 4);
            if (a.x > bv) { bv = a.x; bi = rowbase + 0; }
            if (a.y > bv) { bv = a.y; bi = rowbase + 1; }
            if (a.z > bv) { bv = a.z; bi = rowbase + 2; }
            if (a.w > bv) { bv = a.w; bi = rowbase + 3; }
            if (c.x > bv) { bv = c.x; bi = rowbase + 4; }
            if (c.y > bv) { bv = c.y; bi = rowbase + 5; }
            if (c.z > bv) { bv = c.z; bi = rowbase + 6; }
            if (c.w > bv) { bv = c.w; bi = rowbase + 7; }
        }
        pv[i] = pack_vi(bv, bi);   // bv >= 0 (uniform map), bi always set
    }

    if (tid < NP) {   // boxes start empty (x1==x2) => mask tests inert
        boxes[tid][0] = 0; boxes[tid][1] = 0; boxes[tid][2] = 0; boxes[tid][3] = 0;
    }
    __syncthreads();

    // ======== Phase 2: greedy selection, fully block-local =================
    for (int k = 0; k < NP; ++k) {
        unsigned long long m = pv[0];
        #pragma unroll
        for (int i = 1; i < 8; ++i) if (pv[i] > m) m = pv[i];
        #pragma unroll
        for (int off = 1; off < 64; off <<= 1) {
            const unsigned long long o = __shfl_xor(m, off);
            if (o > m) m = o;
        }
        if (lane == 0) rw[wave] = m;
        __syncthreads();

        if (tid == 0) {
            m = rw[0];
            #pragma unroll
            for (int w = 1; w < 8; ++w) if (rw[w] > m) m = rw[w];
            const int bi = (int)(0xffffffffu - (unsigned)(m & 0xffffffffu));
            const int yc = bi >> 9, xc = bi & 511;
            int x1 = max(0, xc - HALF), x2 = min(WW, xc + HALF);
            int y1 = max(0, yc - HALF), y2 = min(HH, yc + HALF);
            if (x2 - x1 < EPS) { if (x1 == 0) x2 = EPS; else x1 = x2 - EPS; }
            if (y2 - y1 < EPS) { if (y1 == 0) y2 = EPS; else y1 = y2 - EPS; }
            boxes[k][0] = max(x1 - MARGIN, 0);
            boxes[k][1] = min(x2 + MARGIN, WW);
            boxes[k][2] = max(y1 - MARGIN, 0);
            boxes[k][3] = min(y2 + MARGIN, HH);
            sx1[k] = x1; sy1[k] = y1;

            if (slice == 0) {   // one writer per map
                const int o = (b * NP + k) * 4;
                coords_out[o + 0] = (float)x1;
                coords_out[o + 1] = (float)y1;
                coords_out[o + 2] = (float)x2;
                coords_out[o + 3] = (float)y2;
            }
        }
        __syncthreads();

        if (k == NP - 1) break;

        // all boxes -> plain registers (no arrays => no scratch)
        const int b00 = boxes[0][0], b01 = boxes[0][1], b02 = boxes[0][2], b03 = boxes[0][3];
        const int b10 = boxes[1][0], b11 = boxes[1][1], b12 = boxes[1][2], b13 = boxes[1][3];
        const int b20 = boxes[2][0], b21 = boxes[2][1], b22 = boxes[2][2], b23 = boxes[2][3];
        const int b30 = boxes[3][0], b31 = boxes[3][1], b32 = boxes[3][2], b33 = boxes[3][3];
        const int ex1 = boxes[k][0], ex2 = boxes[k][1];
        const int ey1 = boxes[k][2], ey2 = boxes[k][3];
        const int X2 = X1 + 8;

        #pragma unroll
        for (int i = 0; i < 8; ++i) {
            const int ty = (tid >> 6) + (i << 3);
            const int Y1 = ty << 3, Y2 = Y1 + 8;
            if (X1 >= ex2 || X2 <= ex1 || Y1 >= ey2 || Y2 <= ey1) continue;   // untouched
            if (X1 >= ex1 && X2 <= ex2 && Y1 >= ey1 && Y2 <= ey2) {           // fully masked
                pv[i] = 0ULL; continue;
            }
            // perimeter tile: rescan 64 px vs all boxes so far
            float nv = -INFINITY; int ni = 0x7fffffff;
            for (int r = 0; r < 8; ++r) {
                const int y = Y1 + r;
                const int rowbase = y * WW + X1;
                const float4 a = *(const float4*)(um + rowbase);
                const float4 c = *(const float4*)(um + rowbase + 4);
                const float vals[8] = {a.x, a.y, a.z, a.w, c.x, c.y, c.z, c.w};
                #pragma unroll
                for (int j = 0; j < 8; ++j) {
                    const int xe = X1 + j;
                    const bool msk =
                        (y >= b02 && y < b03 && xe >= b00 && xe < b01) ||
                        (y >= b12 && y < b13 && xe >= b10 && xe < b11) ||
                        (y >= b22 && y < b23 && xe >= b20 && xe < b21) ||
                        (y >= b32 && y < b33 && xe >= b30 && xe < b31);
                    if (!msk && vals[j] > nv) { nv = vals[j]; ni = rowbase + j; }
                }
            }
            pv[i] = (ni == 0x7fffffff) ? 0ULL : pack_vi(nv, ni);
        }
        __syncthreads();   // protect rw/boxes reuse next iteration
    }

    // ======== Phase 3: extract own map's slice =============================
    float4* __restrict__ out4 = (float4*)out;
    #pragma unroll
    for (int it = 0; it < 12; ++it) {
        const int il  = slice * F4_PER_SLICE + it * NTHR + tid;  // within-map f4 idx
        const int nc  = il >> 12;            // (n,c) plane, 0..11
        const int n   = nc / 3;
        const int c   = nc - n * 3;
        const int py  = (il >> 5) & 127;
        const int px0 = (il & 31) << 2;

        const int x1 = sx1[n], y1 = sy1[n];
        const float* __restrict__ src =
            images + (((size_t)b * CH + c) * HH + (y1 + py)) * WW + x1 + px0;
        out4[(size_t)b * F4_PER_MAP + il] = make_float4(src[0], src[1], src[2], src[3]);
    }
}

extern "C" void kernel_launch(void* const* d_in, const int* in_sizes, int n_in,
                              void* d_out, int out_size, void* d_ws, size_t ws_size,
                              hipStream_t stream) {
    const float* images = (const float*)d_in[0];
    const float* umaps  = (const float*)d_in[1];
    float* out          = (float*)d_out;

    fused_kernel<<<NBLK, NTHR, 0, stream>>>(images, umaps, out);
}

// Round 8
// 234.005 us; speedup vs baseline: 1.5678x; 1.5678x over previous
//
#include <hip/hip_runtime.h>
#include <math.h>
#include <float.h>

#define BN 32
#define CH 3
#define HH 512
#define WW 512
#define NP 4
#define EPS 128
#define HALF 64
#define MARGIN 32

#define PATCH_ELEMS (BN * NP * CH * EPS * EPS)   // 6291456
#define NT 4096          // 64x64 grid of 8x8 tiles per map
#define TPR 64
#define NBLK 256         // 8 slice-blocks per map; map b -> XCD b&7
#define NTHR 1024
#define F4_PER_MAP (NP * CH * EPS * EPS / 4)     // 49152
#define F4_PER_SLICE (F4_PER_MAP / 8)            // 6144 = 6 * 1024

// Fully self-sufficient blocks: no grid barrier, no workspace, no fences.
// Each block scans its own map into an LDS tile cache (like R6, 48 VGPR,
// no scratch), selects redundantly (deterministic => all 8 blocks of a map
// agree), extracts its 1/8 slice.
__global__ __launch_bounds__(NTHR)
void fused_kernel(const float* __restrict__ images,
                  const float* __restrict__ umaps,
                  float* __restrict__ out)          // patches then coords
{
    const int tid   = threadIdx.x;
    const int lane  = tid & 63;
    const int wave  = tid >> 6;
    const int b     = blockIdx.x & (BN - 1);
    const int slice = blockIdx.x >> 5;
    const float* __restrict__ um = umaps + (size_t)b * HH * WW;
    float* coords_out = out + PATCH_ELEMS;

    __shared__ float tv[NT];
    __shared__ int   ti[NT];
    __shared__ int   boxes[NP][4];   // clipped, margin-expanded ex1,ex2,ey1,ey2
    __shared__ float rv[16];
    __shared__ int   ri[16];
    __shared__ int   sx1[NP], sy1[NP];

    // ======== Phase 1: build own map's tile cache in LDS (4 tiles/thread) ===
    for (int i = 0; i < 4; ++i) {
        const int t  = tid + (i << 10);
        const int tx = t & (TPR - 1), ty = t >> 6;
        const int x0 = tx << 3, y0 = ty << 3;
        float bv = -INFINITY; int bi = 0x7fffffff;
        #pragma unroll
        for (int r = 0; r < 8; ++r) {
            const int rowbase = (y0 + r) * WW + x0;
            const float4 a = *(const float4*)(um + rowbase);
            const float4 c = *(const float4*)(um + rowbase + 4);
            if (a.x > bv) { bv = a.x; bi = rowbase + 0; }
            if (a.y > bv) { bv = a.y; bi = rowbase + 1; }
            if (a.z > bv) { bv = a.z; bi = rowbase + 2; }
            if (a.w > bv) { bv = a.w; bi = rowbase + 3; }
            if (c.x > bv) { bv = c.x; bi = rowbase + 4; }
            if (c.y > bv) { bv = c.y; bi = rowbase + 5; }
            if (c.z > bv) { bv = c.z; bi = rowbase + 6; }
            if (c.w > bv) { bv = c.w; bi = rowbase + 7; }
        }
        tv[t] = bv; ti[t] = bi;
    }
    if (tid < NP) {   // boxes start empty => mask tests inert
        boxes[tid][0] = 0; boxes[tid][1] = 0; boxes[tid][2] = 0; boxes[tid][3] = 0;
    }
    __syncthreads();

    // ======== Phase 2: greedy selection, block-local ========================
    for (int k = 0; k < NP; ++k) {
        // ---- block argmax over 4096 entries ----
        float bv = -INFINITY; int bi = 0x7fffffff;
        #pragma unroll
        for (int i = 0; i < 4; ++i) {
            const int t = tid + (i << 10);
            const float v = tv[t]; const int x = ti[t];
            if (v > bv || (v == bv && x < bi)) { bv = v; bi = x; }
        }
        #pragma unroll
        for (int off = 32; off > 0; off >>= 1) {
            float ov = __shfl_down(bv, off);
            int   oi = __shfl_down(bi, off);
            if (ov > bv || (ov == bv && oi < bi)) { bv = ov; bi = oi; }
        }
        if (lane == 0) { rv[wave] = bv; ri[wave] = bi; }
        __syncthreads();

        if (tid == 0) {
            bv = rv[0]; bi = ri[0];
            #pragma unroll
            for (int w = 1; w < 16; ++w)
                if (rv[w] > bv || (rv[w] == bv && ri[w] < bi)) { bv = rv[w]; bi = ri[w]; }
            const int yc = bi >> 9, xc = bi & 511;
            int x1 = max(0, xc - HALF), x2 = min(WW, xc + HALF);
            int y1 = max(0, yc - HALF), y2 = min(HH, yc + HALF);
            if (x2 - x1 < EPS) { if (x1 == 0) x2 = EPS; else x1 = x2 - EPS; }
            if (y2 - y1 < EPS) { if (y1 == 0) y2 = EPS; else y1 = y2 - EPS; }
            boxes[k][0] = max(x1 - MARGIN, 0);
            boxes[k][1] = min(x2 + MARGIN, WW);
            boxes[k][2] = max(y1 - MARGIN, 0);
            boxes[k][3] = min(y2 + MARGIN, HH);
            sx1[k] = x1; sy1[k] = y1;

            if (slice == 0) {   // one writer per map
                const int o = (b * NP + k) * 4;
                coords_out[o + 0] = (float)x1;
                coords_out[o + 1] = (float)y1;
                coords_out[o + 2] = (float)x2;
                coords_out[o + 3] = (float)y2;
            }
        }
        __syncthreads();

        if (k == NP - 1) break;

        // all boxes -> plain registers (no arrays => no scratch)
        const int b00 = boxes[0][0], b01 = boxes[0][1], b02 = boxes[0][2], b03 = boxes[0][3];
        const int b10 = boxes[1][0], b11 = boxes[1][1], b12 = boxes[1][2], b13 = boxes[1][3];
        const int b20 = boxes[2][0], b21 = boxes[2][1], b22 = boxes[2][2], b23 = boxes[2][3];
        const int b30 = boxes[3][0], b31 = boxes[3][1], b32 = boxes[3][2], b33 = boxes[3][3];
        const int ex1 = boxes[k][0], ex2 = boxes[k][1];
        const int ey1 = boxes[k][2], ey2 = boxes[k][3];

        for (int i = 0; i < 4; ++i) {
            const int t  = tid + (i << 10);
            const int tx = t & (TPR - 1), ty = t >> 6;
            const int X1 = tx << 3, Y1 = ty << 3;
            const int X2 = X1 + 8,  Y2 = Y1 + 8;
            if (X1 >= ex2 || X2 <= ex1 || Y1 >= ey2 || Y2 <= ey1) continue;   // untouched
            if (X1 >= ex1 && X2 <= ex2 && Y1 >= ey1 && Y2 <= ey2) {           // fully masked
                tv[t] = -INFINITY; ti[t] = 0x7fffffff; continue;
            }
            // perimeter tile: rescan 64 px vs all boxes so far
            float nv = -INFINITY; int ni = 0x7fffffff;
            for (int r = 0; r < 8; ++r) {
                const int y = Y1 + r;
                const int rowbase = y * WW + X1;
                const float4 a = *(const float4*)(um + rowbase);
                const float4 c = *(const float4*)(um + rowbase + 4);
                const float vals[8] = {a.x, a.y, a.z, a.w, c.x, c.y, c.z, c.w};
                #pragma unroll
                for (int j = 0; j < 8; ++j) {
                    const int xe = X1 + j;
                    const bool m =
                        (y >= b02 && y < b03 && xe >= b00 && xe < b01) ||
                        (y >= b12 && y < b13 && xe >= b10 && xe < b11) ||
                        (y >= b22 && y < b23 && xe >= b20 && xe < b21) ||
                        (y >= b32 && y < b33 && xe >= b30 && xe < b31);
                    if (!m && vals[j] > nv) { nv = vals[j]; ni = rowbase + j; }
                }
            }
            tv[t] = nv; ti[t] = ni;
        }
        __syncthreads();
    }

    // ======== Phase 3: extract own map's slice ==============================
    float4* __restrict__ out4 = (float4*)out;
    #pragma unroll
    for (int it = 0; it < 6; ++it) {
        const int il  = slice * F4_PER_SLICE + it * NTHR + tid;  // within-map f4 idx
        const int nc  = il >> 12;            // (n,c) plane, 0..11
        const int n   = nc / 3;
        const int c   = nc - n * 3;
        const int py  = (il >> 5) & 127;
        const int px0 = (il & 31) << 2;

        const int x1 = sx1[n], y1 = sy1[n];
        const float* __restrict__ src =
            images + (((size_t)b * CH + c) * HH + (y1 + py)) * WW + x1 + px0;
        out4[(size_t)b * F4_PER_MAP + il] = make_float4(src[0], src[1], src[2], src[3]);
    }
}

extern "C" void kernel_launch(void* const* d_in, const int* in_sizes, int n_in,
                              void* d_out, int out_size, void* d_ws, size_t ws_size,
                              hipStream_t stream) {
    const float* images = (const float*)d_in[0];
    const float* umaps  = (const float*)d_in[1];
    float* out          = (float*)d_out;

    fused_kernel<<<NBLK, NTHR, 0, stream>>>(images, umaps, out);
}